// Round 12
// baseline (2335.961 us; speedup 1.0000x reference)
//
#include <hip/hip_runtime.h>
#include <hip/hip_bf16.h>

#define B_N 4096
#define L_N 32
#define C_N 28
#define H_N 512
#define T_N 32
#define G_N 2048
// K layout (chunks of 32): A: [0..15]=h_hi, [16]=ctx_hi, [17..32]=h_lo, [33]=ctx_lo
// W store: [0..16]=W_hi, [17..33]=W_lo.  MFMA chunks: 51.
// W column packing: within n128-block, tile t (0..7): gate = t&3,
//   unit = n128*32 + (t>>2)*16 + c  -> in-register LSTM epilogue.
// R12: fused ctx via SOFTWARE per-panel sync (graph-capture-safe).
// Block bid produces ctx rows [bid*8,bid*8+8) (panel bid/16) in its prologue,
// release-signals bar[t][bid/16]; consumer (m,n) acquire-spins on bar[t][m]==16
// before k-step 14 (which stages the ctx chunk), with agent acquire fence
// (buffer_inv) to kill stale cross-XCD L2 lines.
#define CHA 34
#define CHSH 4096          // shorts per frag chunk: 8 tiles * 64 lanes * 8
#define ABLK (CHA * CHSH)
#define XS 29              // padded LDS stride for prep_x

typedef __attribute__((ext_vector_type(2))) float f32x2;
typedef __attribute__((ext_vector_type(4))) float f32x4;
typedef __attribute__((ext_vector_type(8))) short s16x8;

static constexpr size_t OFF_WF = 0;                                    // Wf bf16 16*ABLK
static constexpr size_t AB_ONE = (size_t)32 * ABLK * 2;                // 8.9 MB
static constexpr size_t OFF_AB = OFF_WF + (size_t)16 * ABLK * 2;
static constexpr size_t OFF_X  = OFF_AB + 2 * AB_ONE;                  // f32 [4096][32][28]
static constexpr size_t OFF_UA = OFF_X + (size_t)B_N * L_N * C_N * 4;  // f32 [4096][32]
static constexpr size_t OFF_BS = OFF_UA + (size_t)B_N * L_N * 4;       // f32 [2048]
static constexpr size_t OFF_AC = OFF_BS + 8192;                        // accW[4096][32], accO[4096][32]
static constexpr size_t ACC_HALF = (size_t)32 * B_N * 4;               // 512 KB
static constexpr size_t OFF_CS = OFF_AC + 2 * ACC_HALF;                // f32 [4096][512]
static constexpr size_t OFF_BR = OFF_CS + (size_t)B_N * H_N * 4;       // bar u32 [T_N][32]
static constexpr size_t WS_NEED = OFF_BR + (size_t)T_N * 32 * 4;       // ~36 MB

__device__ __forceinline__ short bfbits(__hip_bfloat16 b) {
    union { __hip_bfloat16 b; short s; } v; v.b = b; return v.s;
}
__device__ __forceinline__ float sigmoidf_(float x) { return 1.f / (1.f + __expf(-x)); }
__device__ __forceinline__ float tanhf_(float x) {
    float ax = fabsf(x), e = __expf(-2.f * ax);
    float t = (1.f - e) / (1.f + e);
    return x < 0.f ? -t : t;
}

__global__ __launch_bounds__(256) void fill_out(float* out, float v) {
    int i = blockIdx.x * 256 + threadIdx.x;
    if (i < B_N * 32) out[i] = v;
}

// ---------------- prep_x: x-in-registers + stencil shuffles + scalar weights ----------------
__global__ __launch_bounds__(256) void prep_x(const float* __restrict__ input,
                       const float* __restrict__ mask,
                       const float* __restrict__ w1, const float* __restrict__ b1,
                       const float* __restrict__ cw, const float* __restrict__ cb,
                       float* __restrict__ x, float* __restrict__ ua)
{
    __shared__ float sin[8 * L_N * XS];
    __shared__ float sxb[8 * L_N * XS];
    const float* src = input + (size_t)blockIdx.x * (8 * L_N * C_N);
    for (int i = threadIdx.x; i < 8 * L_N * C_N; i += 256) {
        int lr = i / (L_N * C_N);
        int rem = i - lr * (L_N * C_N);
        int l = rem / C_N, c = rem - l * C_N;
        sin[lr * (L_N * XS) + l * XS + c] = src[i];
    }
    __syncthreads();

    int idx = blockIdx.x * 256 + threadIdx.x;
    int l = idx & 31;
    int wv = threadIdx.x >> 5;
    const float* inb = sin + wv * (L_N * XS);
    float m = mask[idx];

    float x0r[C_N], xm1[C_N], xp1[C_N];
    #pragma unroll
    for (int i = 0; i < C_N; ++i) x0r[i] = inb[l * XS + i];
    #pragma unroll
    for (int i = 0; i < C_N; ++i) {
        float up = __shfl_up(x0r[i], 1, 32);
        float dn = __shfl_down(x0r[i], 1, 32);
        xm1[i] = (l > 0)  ? up : 0.f;
        xp1[i] = (l < 31) ? dn : 0.f;
    }

    float uacc = 0.f;
    float* sxrow = sxb + wv * (L_N * XS) + l * XS;
    #pragma unroll 2
    for (int o = 0; o < C_N; ++o) {
        const float* wo = w1 + o * (C_N * 3);   // wave-uniform -> s_load
        float y0 = b1[o], y1 = 0.f, y2 = 0.f;
        #pragma unroll
        for (int i = 0; i < C_N; ++i) {
            y0 += wo[i * 3 + 0] * xm1[i];
            y1 += wo[i * 3 + 1] * x0r[i];
            y2 += wo[i * 3 + 2] * xp1[i];
        }
        float y = (y0 + y1 + y2) * m;
        float e = (y > 0.f) ? y : (__expf(y) - 1.f);
        float xv = e + inb[l * XS + o];
        sxrow[o] = xv;
        uacc += xv * cw[o];
    }
    ua[idx] = (uacc + cb[0]) * m;
    __syncthreads();
    float* xdst = x + (size_t)blockIdx.x * (8 * L_N * C_N);
    for (int i = threadIdx.x; i < 8 * L_N * C_N; i += 256) {
        int lr = i / (L_N * C_N);
        int rem = i - lr * (L_N * C_N);
        int l2 = rem / C_N, c = rem - l2 * C_N;
        xdst[i] = sxb[lr * (L_N * XS) + l2 * XS + c];
    }
}

// ---------------- prep_wf: frag-major hi/lo weights, gate-in-tile packing ----------------
__global__ __launch_bounds__(256) void prep_wf(const float* __restrict__ w_ih,
                                               const float* __restrict__ w_hh,
                                               short* __restrict__ Wf)
{
    int blk = blockIdx.x;                  // 16*34
    int n128 = blk / CHA, c = blk % CHA;
    bool lo = (c >= 17);
    int kbase = (lo ? (c - 17) : c) * 32;
    short* dst = Wf + ((size_t)n128 * CHA + c) * CHSH;
    for (int g = threadIdx.x; g < 512; g += 256) {
        int j = g >> 6, lane = g & 63;
        int gate = j & 3;
        int unit = n128 * 32 + (j >> 2) * 16 + (lane & 15);
        int srow = gate * H_N + unit;
        int kg = lane >> 4;
        s16x8 out;
        #pragma unroll
        for (int b2 = 0; b2 < 8; ++b2) {
            int k = kbase + kg * 8 + b2;
            float v = 0.f;
            if (k < 512) v = w_hh[(size_t)srow * H_N + k];
            else if (k < 540) v = w_ih[srow * C_N + (k - 512)];
            __hip_bfloat16 hi = __float2bfloat16(v);
            if (lo) out[b2] = bfbits(__float2bfloat16(v - __bfloat162float(hi)));
            else    out[b2] = bfbits(hi);
        }
        *(s16x8*)(dst + g * 8) = out;
    }
}

__global__ void prep_bs(const float* __restrict__ b_ih, const float* __restrict__ b_hh,
                        float* __restrict__ bsum)
{
    int p = blockIdx.x * 256 + threadIdx.x;
    if (p < G_N) {
        int unit = p >> 2, gate = p & 3;
        bsum[p] = b_ih[gate * H_N + unit] + b_hh[gate * H_N + unit];
    }
}

__global__ void prep_zero(unsigned int* __restrict__ a32, float* __restrict__ cst,
                          float* __restrict__ acc, unsigned int* __restrict__ bar)
{
    int idx = blockIdx.x * blockDim.x + threadIdx.x;
    if (idx < B_N * 1088) a32[idx] = 0u;
    if (idx < B_N * H_N) cst[idx] = 0.f;
    if (idx < 2 * 32 * B_N) acc[idx] = 0.f;
    if (idx < T_N * 32) bar[idx] = 0u;
}

// ---------------- params ----------------
struct RParams {
    const float* mask;
    const float* bias_mat;
    const float* fc1_w;
    const float* fc1_b;
    const float* conv2_w;
    const float* conv2_b;
    const short* Wf;
    const short* Ain;
    short* ctxA;           // == Ain buffer, writable (ctx chunk 16/33)
    short* Aout;
    const float* x;
    const float* ua;
    const float* bsum;
    float* accW;           // [4096][32] slot = n*2+wn
    float* accO;           // [4096][32]
    float* cstate;
    unsigned int* bar;     // [T_N][32] producer counters
    float* out;
};

// ---------------- ctx_step: final out column only (t = T_N) ----------------
__global__ __launch_bounds__(256) void ctx_step(RParams P, int t)
{
    __shared__ float sx[4][L_N * C_N];

    const int lane = threadIdx.x & 63;
    const int wave = threadIdx.x >> 6;
    const int row  = blockIdx.x * 4 + wave;

    f32x2 st[7];
    const float* xrow = P.x + (size_t)row * (L_N * C_N);
    #pragma unroll
    for (int q = 0; q < 7; ++q) st[q] = *(const f32x2*)(xrow + (q * 64 + lane) * 2);

    float v = (lane < 32) ? P.accW[row * 32 + lane] : P.accO[row * 32 + (lane - 32)];
    #pragma unroll
    for (int off = 1; off <= 16; off <<= 1) v += __shfl_xor(v, off);
    float aW = __shfl(v, 0);
    float aO = __shfl(v, 32);

    if (t > 0 && lane == 0)
        P.out[row * T_N + (t - 1)] = (aO + P.conv2_b[0]) * P.mask[row * L_N + (t - 1)];

    if (t < T_N) {
        float w_a = aW + P.fc1_b[0];
        int l32 = lane & 31;
        float e = P.ua[row * L_N + l32] + w_a;
        e = (e > 0.f) ? e : 0.01f * e;
        e += P.bias_mat[row * L_N + l32];
        float mx = e;
        #pragma unroll
        for (int off = 16; off > 0; off >>= 1) mx = fmaxf(mx, __shfl_xor(mx, off, 32));
        float pexp = __expf(e - mx);
        float ssum = pexp;
        #pragma unroll
        for (int off = 16; off > 0; off >>= 1) ssum += __shfl_xor(ssum, off, 32);
        float p = pexp / ssum;

        #pragma unroll
        for (int q = 0; q < 7; ++q)
            *(f32x2*)(&sx[wave][(q * 64 + lane) * 2]) = st[q];

        int cc = (lane < C_N) ? lane : 0;
        float ctx = 0.f;
        #pragma unroll
        for (int l = 0; l < L_N; ++l) {
            float al = __shfl(p, l);
            ctx += al * sx[wave][l * C_N + cc];
        }
        if (lane < C_N) {
            int m128 = row >> 7, mt = (row & 127) >> 4, r = row & 15;
            int flane = r + 16 * (lane >> 3);
            short* base = P.Aout + (size_t)m128 * ABLK + mt * 512 + flane * 8 + (lane & 7);
            __hip_bfloat16 hi = __float2bfloat16(ctx);
            base[16 * CHSH] = bfbits(hi);
            base[33 * CHSH] = bfbits(__float2bfloat16(ctx - __bfloat162float(hi)));
        }
    }
}

// ---------------- gemm_cell_step: fused ctx + gemm + LSTM, software per-panel sync ----------------
#define STG_BUF 32768

__global__ __launch_bounds__(256, 2) void gemm_cell_step(RParams P, int t)
{
    __shared__ __align__(16) char smem[65536 + 14336];   // 2 buffers + ctx scratch

    const int tid  = threadIdx.x;
    const int lane = tid & 63;
    const int wave = tid >> 6;
    const int bid  = blockIdx.x;       // 512
    const int xg = bid & 7, gg = bid >> 3;
    const int m  = (xg >> 1) * 8 + (gg & 7);
    const int n  = (xg & 1) * 8 + (gg >> 3);
    const int wm = wave >> 1, wn = wave & 1;

    const short* Af = P.Ain + (size_t)m * ABLK;
    const short* Wg = P.Wf  + (size_t)n * ABLK;

    const short* slab0 = (wave < 2) ? Af : Wg;
    const int slab_lo  = (wave & 1) ? 17 : 0;

    char* bufp0 = smem;
    char* bufp1 = smem + STG_BUF;

    auto stage = [&](char* lbuf, int kk) {
        const short* gp = slab0 + (size_t)(slab_lo + kk) * CHSH + lane * 8;
        char* lb = lbuf + wave * 8192;            // wave-uniform LDS base
        #pragma unroll
        for (int r = 0; r < 8; ++r) {
            __builtin_amdgcn_global_load_lds(
                (const __attribute__((address_space(1))) void*)(gp + r * 512),
                (__attribute__((address_space(3))) void*)(lb + r * 1024),
                16, 0, 0);
        }
    };

    // issue first two stages (async DMA overlaps the ctx prologue)
    stage(bufp0, 0);
    stage(bufp1, 1);

    // ---- ctx prologue: rows [bid*8, bid*8+8), 2 rows per wave, no duplication ----
    {
        float* myxs = (float*)(smem + 65536) + wave * (L_N * C_N);
        #pragma unroll
        for (int r2 = 0; r2 < 2; ++r2) {
            int row = bid * 8 + wave * 2 + r2;
            const float* xrow = P.x + (size_t)row * (L_N * C_N);
            f32x2 st[7];
            #pragma unroll
            for (int q = 0; q < 7; ++q) st[q] = *(const f32x2*)(xrow + (q * 64 + lane) * 2);
            float v = (lane < 32) ? P.accW[row * 32 + lane] : P.accO[row * 32 + (lane - 32)];
            #pragma unroll
            for (int off = 1; off <= 16; off <<= 1) v += __shfl_xor(v, off);
            float aW = __shfl(v, 0);
            float aO = __shfl(v, 32);
            if (t > 0 && lane == 0)
                P.out[(size_t)row * T_N + (t - 1)] =
                    (aO + P.conv2_b[0]) * P.mask[row * L_N + (t - 1)];
            float w_a = aW + P.fc1_b[0];
            int l32 = lane & 31;
            float e = P.ua[row * L_N + l32] + w_a;
            e = (e > 0.f) ? e : 0.01f * e;
            e += P.bias_mat[row * L_N + l32];
            float mx = e;
            #pragma unroll
            for (int off = 16; off > 0; off >>= 1) mx = fmaxf(mx, __shfl_xor(mx, off, 32));
            float pexp = __expf(e - mx);
            float ssum = pexp;
            #pragma unroll
            for (int off = 16; off > 0; off >>= 1) ssum += __shfl_xor(ssum, off, 32);
            float p = pexp / ssum;
            #pragma unroll
            for (int q = 0; q < 7; ++q)
                *(f32x2*)(myxs + (q * 64 + lane) * 2) = st[q];
            int cc = (lane < C_N) ? lane : 0;
            float ctx = 0.f;
            #pragma unroll
            for (int l = 0; l < L_N; ++l) {
                float al = __shfl(p, l);
                ctx += al * myxs[l * C_N + cc];
            }
            if (lane < C_N) {
                int m128p = row >> 7, mt = (row & 127) >> 4, rr = row & 15;
                int flane = rr + 16 * (lane >> 3);
                short* base = P.ctxA + (size_t)m128p * ABLK + mt * 512 + flane * 8 + (lane & 7);
                __hip_bfloat16 hi = __float2bfloat16(ctx);
                base[16 * CHSH] = bfbits(hi);
                base[33 * CHSH] = bfbits(__float2bfloat16(ctx - __bfloat162float(hi)));
            }
        }
    }
    // producer signal: all waves' ctx stores drained (syncthreads waits vmcnt),
    // then release fence (buffer_wbl2) + counter bump at agent scope.
    __syncthreads();
    if (tid == 0) {
        __builtin_amdgcn_fence(__ATOMIC_RELEASE, "agent");
        __hip_atomic_fetch_add(&P.bar[t * 32 + (bid >> 4)], 1u,
                               __ATOMIC_RELEASE, __HIP_MEMORY_SCOPE_AGENT);
    }

    int aoff[4], woff[4];
    #pragma unroll
    for (int i = 0; i < 4; ++i) {
        aoff[i] = ((wm * 4 + i) * 64 + lane) * 16;
        woff[i] = ((wn * 4 + i) * 64 + lane) * 16;
    }

    f32x4 acc[4][4];
    #pragma unroll
    for (int i = 0; i < 4; ++i)
        #pragma unroll
        for (int j = 0; j < 4; ++j)
            acc[i][j] = (f32x4){0.f, 0.f, 0.f, 0.f};

    s16x8 RA[16], RB[16];
    auto ldfr = [&](const char* b, s16x8 (&R)[16]) {
        #pragma unroll
        for (int i = 0; i < 4; ++i) {
            R[i]      = *(const s16x8*)(b + aoff[i]);
            R[4 + i]  = *(const s16x8*)(b + 8192 + aoff[i]);
            R[8 + i]  = *(const s16x8*)(b + 16384 + woff[i]);
            R[12 + i] = *(const s16x8*)(b + 24576 + woff[i]);
        }
    };
    auto domm = [&](s16x8 (&R)[16]) {
        #pragma unroll
        for (int i = 0; i < 4; ++i)
            #pragma unroll
            for (int j = 0; j < 4; ++j)
                acc[i][j] = __builtin_amdgcn_mfma_f32_16x16x32_bf16(R[i], R[8 + j], acc[i][j], 0, 0, 0);
        #pragma unroll
        for (int i = 0; i < 4; ++i)
            #pragma unroll
            for (int j = 0; j < 4; ++j)
                acc[i][j] = __builtin_amdgcn_mfma_f32_16x16x32_bf16(R[4 + i], R[8 + j], acc[i][j], 0, 0, 0);
        #pragma unroll
        for (int i = 0; i < 4; ++i)
            #pragma unroll
            for (int j = 0; j < 4; ++j)
                acc[i][j] = __builtin_amdgcn_mfma_f32_16x16x32_bf16(R[i], R[12 + j], acc[i][j], 0, 0, 0);
    };

    auto step_full = [&](int kk, s16x8 (&Rc)[16], s16x8 (&Rn)[16], char* bcur, char* bnext) {
        asm volatile("s_waitcnt vmcnt(0) lgkmcnt(0)" ::: "memory");
        __builtin_amdgcn_s_barrier();
        __builtin_amdgcn_sched_barrier(0);
        stage(bcur, kk + 2);
        ldfr(bnext, Rn);
        domm(Rc);
        #pragma unroll
        for (int g = 0; g < 8; ++g) {
            __builtin_amdgcn_sched_group_barrier(0x010, 1, 0);  // 1 VMEM (global_load_lds)
            __builtin_amdgcn_sched_group_barrier(0x100, 2, 0);  // 2 DS_READ
            __builtin_amdgcn_sched_group_barrier(0x008, 6, 0);  // 6 MFMA
        }
        __builtin_amdgcn_sched_barrier(0);
    };
    auto step_nos = [&](s16x8 (&Rc)[16], s16x8 (&Rn)[16], char* bnext) {
        asm volatile("s_waitcnt vmcnt(0) lgkmcnt(0)" ::: "memory");
        __builtin_amdgcn_s_barrier();
        __builtin_amdgcn_sched_barrier(0);
        ldfr(bnext, Rn);
        domm(Rc);
        #pragma unroll
        for (int g = 0; g < 8; ++g) {
            __builtin_amdgcn_sched_group_barrier(0x100, 2, 0);
            __builtin_amdgcn_sched_group_barrier(0x008, 6, 0);
        }
        __builtin_amdgcn_sched_barrier(0);
    };
    auto step_last = [&](s16x8 (&Rc)[16]) {
        asm volatile("s_waitcnt vmcnt(0) lgkmcnt(0)" ::: "memory");
        __builtin_amdgcn_s_barrier();
        __builtin_amdgcn_sched_barrier(0);
        domm(Rc);
        __builtin_amdgcn_sched_barrier(0);
    };

    asm volatile("s_waitcnt vmcnt(8)" ::: "memory");   // buf0 staged (buf1 in flight)
    __builtin_amdgcn_s_barrier();
    ldfr(bufp0, RA);

    // steps 0..13: stage chunks 2..15 (h/W only)
    for (int kp = 0; kp < 7; ++kp) {
        step_full(2 * kp,     RA, RB, bufp0, bufp1);
        step_full(2 * kp + 1, RB, RA, bufp1, bufp0);
    }

    // consumer wait: my panel's 16 producers have release-signaled.
    if (tid == 0) {
        while (__hip_atomic_load(&P.bar[t * 32 + m], __ATOMIC_ACQUIRE,
                                 __HIP_MEMORY_SCOPE_AGENT) < 16u)
            __builtin_amdgcn_s_sleep(1);
    }
    __syncthreads();
    __builtin_amdgcn_fence(__ATOMIC_ACQUIRE, "agent");   // buffer_inv: drop stale L2 lines

    step_full(14, RA, RB, bufp0, bufp1);   // stages chunk 16 into bufp0
    step_nos(RB, RA, bufp0);               // kk=15: ldfr chunk 16 from bufp0
    step_last(RA);                         // kk=16

    // ---- epilogue (in-register LSTM: thread owns unit = n*32+wn*16+(lane&15)) ----
    __syncthreads();
    short* hasm = (short*)smem;              // hi 8KB @0, lo 8KB @8192
    {
        int u15 = lane & 15, rq = lane >> 4;
        int unit = n * 32 + wn * 16 + u15;
        float cpre[4][4];
        #pragma unroll
        for (int i = 0; i < 4; ++i)
            #pragma unroll
            for (int r = 0; r < 4; ++r)
                cpre[i][r] = P.cstate[(size_t)(m * 128 + wm * 64 + i * 16 + rq * 4 + r) * H_N + unit];
        f32x4 bsv = *(const f32x4*)(P.bsum + unit * 4);
        float f1v = P.fc1_w[unit];
        float c2v = P.conv2_w[unit];
        const int fl16 = 16 * (wn * 2 + (u15 >> 3));
        const int slot = u15 & 7;
        #pragma unroll
        for (int i = 0; i < 4; ++i) {
            #pragma unroll
            for (int r = 0; r < 4; ++r) {
                int grow = m * 128 + wm * 64 + i * 16 + rq * 4 + r;
                float pi = acc[i][0][r] + bsv.x;
                float pf = acc[i][1][r] + bsv.y;
                float pg = acc[i][2][r] + bsv.z;
                float po = acc[i][3][r] + bsv.w;
                float c = sigmoidf_(pf) * cpre[i][r] + sigmoidf_(pi) * tanhf_(pg);
                P.cstate[(size_t)grow * H_N + unit] = c;
                float h = sigmoidf_(po) * tanhf_(c);
                __hip_bfloat16 hi = __float2bfloat16(h);
                int fo = (wm * 4 + i) * 512 + (rq * 4 + r + fl16) * 8 + slot;
                hasm[fo]        = bfbits(hi);
                hasm[4096 + fo] = bfbits(__float2bfloat16(h - __bfloat162float(hi)));
                float wd = f1v * h, od = c2v * h;
                #pragma unroll
                for (int off = 8; off > 0; off >>= 1) {
                    wd += __shfl_xor(wd, off);
                    od += __shfl_xor(od, off);
                }
                if (u15 == 0) {
                    P.accW[(size_t)grow * 32 + (n * 2 + wn)] = wd;
                    P.accO[(size_t)grow * 32 + (n * 2 + wn)] = od;
                }
            }
        }
    }
    __syncthreads();
    short* dhi = P.Aout + (size_t)m * ABLK + (size_t)n * CHSH;
    short* dlo = P.Aout + (size_t)m * ABLK + (size_t)(17 + n) * CHSH;
    *(s16x8*)(dhi + tid * 16)     = *(const s16x8*)(hasm + tid * 16);
    *(s16x8*)(dhi + tid * 16 + 8) = *(const s16x8*)(hasm + tid * 16 + 8);
    *(s16x8*)(dlo + tid * 16)     = *(const s16x8*)(hasm + 4096 + tid * 16);
    *(s16x8*)(dlo + tid * 16 + 8) = *(const s16x8*)(hasm + 4096 + tid * 16 + 8);
}

extern "C" void kernel_launch(void* const* d_in, const int* in_sizes, int n_in,
                              void* d_out, int out_size, void* d_ws, size_t ws_size,
                              hipStream_t stream)
{
    float* out = (float*)d_out;
    if (ws_size < WS_NEED) { fill_out<<<512, 256, 0, stream>>>(out, 4000.f); return; }

    const float* input = (const float*)d_in[0];
    const float* mask  = (const float*)d_in[1];
    const float* biasm = (const float*)d_in[2];
    const float* w1    = (const float*)d_in[3];
    const float* b1    = (const float*)d_in[4];
    const float* cw    = (const float*)d_in[5];
    const float* cb    = (const float*)d_in[6];
    const float* w_ih  = (const float*)d_in[7];
    const float* w_hh  = (const float*)d_in[8];
    const float* b_ih  = (const float*)d_in[9];
    const float* b_hh  = (const float*)d_in[10];
    const float* fc1w  = (const float*)d_in[11];
    const float* fc1b  = (const float*)d_in[12];
    const float* c2w   = (const float*)d_in[13];
    const float* c2b   = (const float*)d_in[14];

    char* ws = (char*)d_ws;
    short* Wf = (short*)(ws + OFF_WF);
    short* A0 = (short*)(ws + OFF_AB);
    short* A1 = (short*)(ws + OFF_AB + AB_ONE);
    float* x    = (float*)(ws + OFF_X);
    float* ua   = (float*)(ws + OFF_UA);
    float* bsum = (float*)(ws + OFF_BS);
    float* accW = (float*)(ws + OFF_AC);
    float* accO = (float*)(ws + OFF_AC + ACC_HALF);
    float* cst  = (float*)(ws + OFF_CS);
    unsigned int* bar = (unsigned int*)(ws + OFF_BR);

    prep_x<<<(B_N * L_N) / 256, 256, 0, stream>>>(input, mask, w1, b1, cw, cb, x, ua);
    prep_wf<<<16 * CHA, 256, 0, stream>>>(w_ih, w_hh, Wf);
    prep_bs<<<(G_N + 255) / 256, 256, 0, stream>>>(b_ih, b_hh, bsum);
    prep_zero<<<(B_N * 1088 + 255) / 256, 256, 0, stream>>>((unsigned int*)A0, cst, accW, bar);

    RParams P;
    P.mask = mask; P.bias_mat = biasm; P.fc1_w = fc1w; P.fc1_b = fc1b;
    P.conv2_w = c2w; P.conv2_b = c2b; P.Wf = Wf;
    P.x = x; P.ua = ua; P.bsum = bsum; P.accW = accW; P.accO = accO;
    P.cstate = cst; P.bar = bar; P.out = out;

    short* bufs[2] = { A0, A1 };
    for (int t = 0; t < T_N; ++t) {
        P.Ain  = bufs[t & 1];
        P.ctxA = bufs[t & 1];
        P.Aout = bufs[(t + 1) & 1];
        gemm_cell_step<<<512, 256, 0, stream>>>(P, t);
    }
    P.Ain  = bufs[T_N & 1];
    P.ctxA = bufs[T_N & 1];
    P.Aout = bufs[T_N & 1];
    ctx_step<<<B_N / 4, 256, 0, stream>>>(P, T_N);
}

// Round 14
// 1363.074 us; speedup vs baseline: 1.7137x; 1.7137x over previous
//
#include <hip/hip_runtime.h>
#include <hip/hip_bf16.h>

#define B_N 4096
#define L_N 32
#define C_N 28
#define H_N 512
#define T_N 32
#define G_N 2048
// K layout (chunks of 32): A: [0..15]=h_hi, [16]=ctx_hi, [17..32]=h_lo, [33]=ctx_lo
// W store: [0..16]=W_hi, [17..33]=W_lo.  MFMA chunks: 51.
// W column packing: within n128-block, tile t (0..7): gate = t&3,
//   unit = n128*32 + (t>>2)*16 + c  -> in-register LSTM epilogue.
// R14 = R10 verbatim (best verified: 1335 us): M=128 grid 512, LDS dbuf +
// reg-prefetch, SGB-interleaved k-step (8 x {1 VMEM, 2 DS_READ, 6 MFMA}).
// R13's W_lo drop FAILED correctness (absmax 0.106 > 0.068) -- full hi/lo
// W must stay. R12's software-sync fusion passed but cost +1000us (acquire
// fence kills L2; serialized prologue). This structure is the measured
// optimum of 13 explored variants.
#define CHA 34
#define CHSH 4096          // shorts per frag chunk: 8 tiles * 64 lanes * 8
#define ABLK (CHA * CHSH)
#define XS 29              // padded LDS stride for prep_x

typedef __attribute__((ext_vector_type(2))) float f32x2;
typedef __attribute__((ext_vector_type(4))) float f32x4;
typedef __attribute__((ext_vector_type(8))) short s16x8;

static constexpr size_t OFF_WF = 0;                                    // Wf bf16 16*ABLK
static constexpr size_t AB_ONE = (size_t)32 * ABLK * 2;                // 8.9 MB
static constexpr size_t OFF_AB = OFF_WF + (size_t)16 * ABLK * 2;
static constexpr size_t OFF_X  = OFF_AB + 2 * AB_ONE;                  // f32 [4096][32][28]
static constexpr size_t OFF_UA = OFF_X + (size_t)B_N * L_N * C_N * 4;  // f32 [4096][32]
static constexpr size_t OFF_BS = OFF_UA + (size_t)B_N * L_N * 4;       // f32 [2048]
static constexpr size_t OFF_AC = OFF_BS + 8192;                        // accW[4096][32], accO[4096][32]
static constexpr size_t ACC_HALF = (size_t)32 * B_N * 4;               // 512 KB
static constexpr size_t OFF_CS = OFF_AC + 2 * ACC_HALF;                // f32 [4096][512]
static constexpr size_t WS_NEED = OFF_CS + (size_t)B_N * H_N * 4;      // ~36 MB

__device__ __forceinline__ short bfbits(__hip_bfloat16 b) {
    union { __hip_bfloat16 b; short s; } v; v.b = b; return v.s;
}
__device__ __forceinline__ float sigmoidf_(float x) { return 1.f / (1.f + __expf(-x)); }
__device__ __forceinline__ float tanhf_(float x) {
    float ax = fabsf(x), e = __expf(-2.f * ax);
    float t = (1.f - e) / (1.f + e);
    return x < 0.f ? -t : t;
}

__global__ __launch_bounds__(256) void fill_out(float* out, float v) {
    int i = blockIdx.x * 256 + threadIdx.x;
    if (i < B_N * 32) out[i] = v;
}

// ---------------- prep_x: x-in-registers + stencil shuffles + scalar weights ----------------
__global__ __launch_bounds__(256) void prep_x(const float* __restrict__ input,
                       const float* __restrict__ mask,
                       const float* __restrict__ w1, const float* __restrict__ b1,
                       const float* __restrict__ cw, const float* __restrict__ cb,
                       float* __restrict__ x, float* __restrict__ ua)
{
    __shared__ float sin[8 * L_N * XS];
    __shared__ float sxb[8 * L_N * XS];
    const float* src = input + (size_t)blockIdx.x * (8 * L_N * C_N);
    for (int i = threadIdx.x; i < 8 * L_N * C_N; i += 256) {
        int lr = i / (L_N * C_N);
        int rem = i - lr * (L_N * C_N);
        int l = rem / C_N, c = rem - l * C_N;
        sin[lr * (L_N * XS) + l * XS + c] = src[i];
    }
    __syncthreads();

    int idx = blockIdx.x * 256 + threadIdx.x;
    int l = idx & 31;
    int wv = threadIdx.x >> 5;
    const float* inb = sin + wv * (L_N * XS);
    float m = mask[idx];

    float x0r[C_N], xm1[C_N], xp1[C_N];
    #pragma unroll
    for (int i = 0; i < C_N; ++i) x0r[i] = inb[l * XS + i];
    #pragma unroll
    for (int i = 0; i < C_N; ++i) {
        float up = __shfl_up(x0r[i], 1, 32);
        float dn = __shfl_down(x0r[i], 1, 32);
        xm1[i] = (l > 0)  ? up : 0.f;
        xp1[i] = (l < 31) ? dn : 0.f;
    }

    float uacc = 0.f;
    float* sxrow = sxb + wv * (L_N * XS) + l * XS;
    #pragma unroll 2
    for (int o = 0; o < C_N; ++o) {
        const float* wo = w1 + o * (C_N * 3);   // wave-uniform -> s_load
        float y0 = b1[o], y1 = 0.f, y2 = 0.f;
        #pragma unroll
        for (int i = 0; i < C_N; ++i) {
            y0 += wo[i * 3 + 0] * xm1[i];
            y1 += wo[i * 3 + 1] * x0r[i];
            y2 += wo[i * 3 + 2] * xp1[i];
        }
        float y = (y0 + y1 + y2) * m;
        float e = (y > 0.f) ? y : (__expf(y) - 1.f);
        float xv = e + inb[l * XS + o];
        sxrow[o] = xv;
        uacc += xv * cw[o];
    }
    ua[idx] = (uacc + cb[0]) * m;
    __syncthreads();
    float* xdst = x + (size_t)blockIdx.x * (8 * L_N * C_N);
    for (int i = threadIdx.x; i < 8 * L_N * C_N; i += 256) {
        int lr = i / (L_N * C_N);
        int rem = i - lr * (L_N * C_N);
        int l2 = rem / C_N, c = rem - l2 * C_N;
        xdst[i] = sxb[lr * (L_N * XS) + l2 * XS + c];
    }
}

// ---------------- prep_wf: frag-major hi/lo weights, gate-in-tile packing ----------------
__global__ __launch_bounds__(256) void prep_wf(const float* __restrict__ w_ih,
                                               const float* __restrict__ w_hh,
                                               short* __restrict__ Wf)
{
    int blk = blockIdx.x;                  // 16*34
    int n128 = blk / CHA, c = blk % CHA;
    bool lo = (c >= 17);
    int kbase = (lo ? (c - 17) : c) * 32;
    short* dst = Wf + ((size_t)n128 * CHA + c) * CHSH;
    for (int g = threadIdx.x; g < 512; g += 256) {
        int j = g >> 6, lane = g & 63;
        int gate = j & 3;
        int unit = n128 * 32 + (j >> 2) * 16 + (lane & 15);
        int srow = gate * H_N + unit;
        int kg = lane >> 4;
        s16x8 out;
        #pragma unroll
        for (int b2 = 0; b2 < 8; ++b2) {
            int k = kbase + kg * 8 + b2;
            float v = 0.f;
            if (k < 512) v = w_hh[(size_t)srow * H_N + k];
            else if (k < 540) v = w_ih[srow * C_N + (k - 512)];
            __hip_bfloat16 hi = __float2bfloat16(v);
            if (lo) out[b2] = bfbits(__float2bfloat16(v - __bfloat162float(hi)));
            else    out[b2] = bfbits(hi);
        }
        *(s16x8*)(dst + g * 8) = out;
    }
}

__global__ void prep_bs(const float* __restrict__ b_ih, const float* __restrict__ b_hh,
                        float* __restrict__ bsum)
{
    int p = blockIdx.x * 256 + threadIdx.x;
    if (p < G_N) {
        int unit = p >> 2, gate = p & 3;
        bsum[p] = b_ih[gate * H_N + unit] + b_hh[gate * H_N + unit];
    }
}

__global__ void prep_zero(unsigned int* __restrict__ a32, float* __restrict__ cst,
                          float* __restrict__ acc)
{
    int idx = blockIdx.x * blockDim.x + threadIdx.x;
    if (idx < B_N * 1088) a32[idx] = 0u;
    if (idx < B_N * H_N) cst[idx] = 0.f;
    if (idx < 2 * 32 * B_N) acc[idx] = 0.f;
}

// ---------------- params ----------------
struct RParams {
    const float* mask;
    const float* bias_mat;
    const float* fc1_w;
    const float* fc1_b;
    const float* conv2_w;
    const float* conv2_b;
    const short* Wf;
    const short* Ain;
    short* Aout;
    const float* x;
    const float* ua;
    const float* bsum;
    float* accW;           // [4096][32] slot = n*2+wn
    float* accO;           // [4096][32]
    float* cstate;
    float* out;
};

// ---------------- ctx_step: sum 32 partial slots; softmax+context (LDS-staged x) ----------------
__global__ __launch_bounds__(256) void ctx_step(RParams P, int t)
{
    __shared__ float sx[4][L_N * C_N];

    const int lane = threadIdx.x & 63;
    const int wave = threadIdx.x >> 6;
    const int row  = blockIdx.x * 4 + wave;

    f32x2 st[7];
    const float* xrow = P.x + (size_t)row * (L_N * C_N);
    #pragma unroll
    for (int q = 0; q < 7; ++q) st[q] = *(const f32x2*)(xrow + (q * 64 + lane) * 2);

    float v = (lane < 32) ? P.accW[row * 32 + lane] : P.accO[row * 32 + (lane - 32)];
    #pragma unroll
    for (int off = 1; off <= 16; off <<= 1) v += __shfl_xor(v, off);
    float aW = __shfl(v, 0);
    float aO = __shfl(v, 32);

    if (t > 0 && lane == 0)
        P.out[row * T_N + (t - 1)] = (aO + P.conv2_b[0]) * P.mask[row * L_N + (t - 1)];

    if (t < T_N) {
        float w_a = aW + P.fc1_b[0];
        int l32 = lane & 31;
        float e = P.ua[row * L_N + l32] + w_a;
        e = (e > 0.f) ? e : 0.01f * e;
        e += P.bias_mat[row * L_N + l32];
        float mx = e;
        #pragma unroll
        for (int off = 16; off > 0; off >>= 1) mx = fmaxf(mx, __shfl_xor(mx, off, 32));
        float pexp = __expf(e - mx);
        float ssum = pexp;
        #pragma unroll
        for (int off = 16; off > 0; off >>= 1) ssum += __shfl_xor(ssum, off, 32);
        float p = pexp / ssum;

        #pragma unroll
        for (int q = 0; q < 7; ++q)
            *(f32x2*)(&sx[wave][(q * 64 + lane) * 2]) = st[q];

        int cc = (lane < C_N) ? lane : 0;
        float ctx = 0.f;
        #pragma unroll
        for (int l = 0; l < L_N; ++l) {
            float al = __shfl(p, l);
            ctx += al * sx[wave][l * C_N + cc];
        }
        if (lane < C_N) {
            int m128 = row >> 7, mt = (row & 127) >> 4, r = row & 15;
            int flane = r + 16 * (lane >> 3);
            short* base = P.Aout + (size_t)m128 * ABLK + mt * 512 + flane * 8 + (lane & 7);
            __hip_bfloat16 hi = __float2bfloat16(ctx);
            base[16 * CHSH] = bfbits(hi);
            base[33 * CHSH] = bfbits(__float2bfloat16(ctx - __bfloat162float(hi)));
        }
    }
}

// ---------------- gemm_cell_step: M=128, LDS dbuf + reg-prefetch, SGB-interleaved ----------------
#define STG_BUF 32768

__global__ __launch_bounds__(256, 2) void gemm_cell_step(RParams P)
{
    __shared__ __align__(16) char smem[65536];

    const int tid  = threadIdx.x;
    const int lane = tid & 63;
    const int wave = tid >> 6;
    const int bid  = blockIdx.x;       // 512
    const int xg = bid & 7, gg = bid >> 3;
    const int m  = (xg >> 1) * 8 + (gg & 7);
    const int n  = (xg & 1) * 8 + (gg >> 3);
    const int wm = wave >> 1, wn = wave & 1;

    const short* Af = P.Ain + (size_t)m * ABLK;
    const short* Wg = P.Wf  + (size_t)n * ABLK;

    const short* slab0 = (wave < 2) ? Af : Wg;
    const int slab_lo  = (wave & 1) ? 17 : 0;

    char* bufp0 = smem;
    char* bufp1 = smem + STG_BUF;

    auto stage = [&](char* lbuf, int kk) {
        const short* gp = slab0 + (size_t)(slab_lo + kk) * CHSH + lane * 8;
        char* lb = lbuf + wave * 8192;            // wave-uniform LDS base
        #pragma unroll
        for (int r = 0; r < 8; ++r) {
            __builtin_amdgcn_global_load_lds(
                (const __attribute__((address_space(1))) void*)(gp + r * 512),
                (__attribute__((address_space(3))) void*)(lb + r * 1024),
                16, 0, 0);
        }
    };

    int aoff[4], woff[4];
    #pragma unroll
    for (int i = 0; i < 4; ++i) {
        aoff[i] = ((wm * 4 + i) * 64 + lane) * 16;
        woff[i] = ((wn * 4 + i) * 64 + lane) * 16;
    }

    f32x4 acc[4][4];
    #pragma unroll
    for (int i = 0; i < 4; ++i)
        #pragma unroll
        for (int j = 0; j < 4; ++j)
            acc[i][j] = (f32x4){0.f, 0.f, 0.f, 0.f};

    s16x8 RA[16], RB[16];
    auto ldfr = [&](const char* b, s16x8 (&R)[16]) {
        #pragma unroll
        for (int i = 0; i < 4; ++i) {
            R[i]      = *(const s16x8*)(b + aoff[i]);
            R[4 + i]  = *(const s16x8*)(b + 8192 + aoff[i]);
            R[8 + i]  = *(const s16x8*)(b + 16384 + woff[i]);
            R[12 + i] = *(const s16x8*)(b + 24576 + woff[i]);
        }
    };
    auto domm = [&](s16x8 (&R)[16]) {
        #pragma unroll
        for (int i = 0; i < 4; ++i)
            #pragma unroll
            for (int j = 0; j < 4; ++j)
                acc[i][j] = __builtin_amdgcn_mfma_f32_16x16x32_bf16(R[i], R[8 + j], acc[i][j], 0, 0, 0);
        #pragma unroll
        for (int i = 0; i < 4; ++i)
            #pragma unroll
            for (int j = 0; j < 4; ++j)
                acc[i][j] = __builtin_amdgcn_mfma_f32_16x16x32_bf16(R[4 + i], R[8 + j], acc[i][j], 0, 0, 0);
        #pragma unroll
        for (int i = 0; i < 4; ++i)
            #pragma unroll
            for (int j = 0; j < 4; ++j)
                acc[i][j] = __builtin_amdgcn_mfma_f32_16x16x32_bf16(R[i], R[12 + j], acc[i][j], 0, 0, 0);
    };

    // full step: 8 VMEM (stage) + 16 DS_READ (prefetch) + 48 MFMA, SGB-interleaved
    auto step_full = [&](int kk, s16x8 (&Rc)[16], s16x8 (&Rn)[16], char* bcur, char* bnext) {
        asm volatile("s_waitcnt vmcnt(0) lgkmcnt(0)" ::: "memory");
        __builtin_amdgcn_s_barrier();
        __builtin_amdgcn_sched_barrier(0);
        stage(bcur, kk + 2);
        ldfr(bnext, Rn);
        domm(Rc);
        #pragma unroll
        for (int g = 0; g < 8; ++g) {
            __builtin_amdgcn_sched_group_barrier(0x010, 1, 0);  // 1 VMEM (global_load_lds)
            __builtin_amdgcn_sched_group_barrier(0x100, 2, 0);  // 2 DS_READ
            __builtin_amdgcn_sched_group_barrier(0x008, 6, 0);  // 6 MFMA
        }
        __builtin_amdgcn_sched_barrier(0);
    };
    // no-stage step (kk==15): 16 DS_READ + 48 MFMA
    auto step_nos = [&](s16x8 (&Rc)[16], s16x8 (&Rn)[16], char* bnext) {
        asm volatile("s_waitcnt vmcnt(0) lgkmcnt(0)" ::: "memory");
        __builtin_amdgcn_s_barrier();
        __builtin_amdgcn_sched_barrier(0);
        ldfr(bnext, Rn);
        domm(Rc);
        #pragma unroll
        for (int g = 0; g < 8; ++g) {
            __builtin_amdgcn_sched_group_barrier(0x100, 2, 0);
            __builtin_amdgcn_sched_group_barrier(0x008, 6, 0);
        }
        __builtin_amdgcn_sched_barrier(0);
    };
    // last step (kk==16): MFMA only
    auto step_last = [&](s16x8 (&Rc)[16]) {
        asm volatile("s_waitcnt vmcnt(0) lgkmcnt(0)" ::: "memory");
        __builtin_amdgcn_s_barrier();
        __builtin_amdgcn_sched_barrier(0);
        domm(Rc);
        __builtin_amdgcn_sched_barrier(0);
    };

    stage(bufp0, 0);
    asm volatile("s_waitcnt vmcnt(0)" ::: "memory");
    __builtin_amdgcn_s_barrier();
    stage(bufp1, 1);
    ldfr(bufp0, RA);

    for (int kp = 0; kp < 7; ++kp) {
        step_full(2 * kp,     RA, RB, bufp0, bufp1);
        step_full(2 * kp + 1, RB, RA, bufp1, bufp0);
    }
    step_full(14, RA, RB, bufp0, bufp1);   // stages chunk 16 into bufp0
    step_nos(RB, RA, bufp0);               // kk=15: ldfr chunk 16 from bufp0
    step_last(RA);                         // kk=16

    // ---- epilogue (in-register LSTM: thread owns unit = n*32+wn*16+(lane&15)) ----
    __syncthreads();
    short* hasm = (short*)smem;              // hi 8KB @0, lo 8KB @8192
    {
        int u15 = lane & 15, rq = lane >> 4;
        int unit = n * 32 + wn * 16 + u15;
        float cpre[4][4];
        #pragma unroll
        for (int i = 0; i < 4; ++i)
            #pragma unroll
            for (int r = 0; r < 4; ++r)
                cpre[i][r] = P.cstate[(size_t)(m * 128 + wm * 64 + i * 16 + rq * 4 + r) * H_N + unit];
        f32x4 bsv = *(const f32x4*)(P.bsum + unit * 4);
        float f1v = P.fc1_w[unit];
        float c2v = P.conv2_w[unit];
        const int fl16 = 16 * (wn * 2 + (u15 >> 3));
        const int slot = u15 & 7;
        #pragma unroll
        for (int i = 0; i < 4; ++i) {
            #pragma unroll
            for (int r = 0; r < 4; ++r) {
                int grow = m * 128 + wm * 64 + i * 16 + rq * 4 + r;
                float pi = acc[i][0][r] + bsv.x;
                float pf = acc[i][1][r] + bsv.y;
                float pg = acc[i][2][r] + bsv.z;
                float po = acc[i][3][r] + bsv.w;
                float c = sigmoidf_(pf) * cpre[i][r] + sigmoidf_(pi) * tanhf_(pg);
                P.cstate[(size_t)grow * H_N + unit] = c;
                float h = sigmoidf_(po) * tanhf_(c);
                __hip_bfloat16 hi = __float2bfloat16(h);
                int fo = (wm * 4 + i) * 512 + (rq * 4 + r + fl16) * 8 + slot;
                hasm[fo]        = bfbits(hi);
                hasm[4096 + fo] = bfbits(__float2bfloat16(h - __bfloat162float(hi)));
                float wd = f1v * h, od = c2v * h;
                #pragma unroll
                for (int off = 8; off > 0; off >>= 1) {
                    wd += __shfl_xor(wd, off);
                    od += __shfl_xor(od, off);
                }
                if (u15 == 0) {
                    P.accW[(size_t)grow * 32 + (n * 2 + wn)] = wd;
                    P.accO[(size_t)grow * 32 + (n * 2 + wn)] = od;
                }
            }
        }
    }
    __syncthreads();
    short* dhi = P.Aout + (size_t)m * ABLK + (size_t)n * CHSH;
    short* dlo = P.Aout + (size_t)m * ABLK + (size_t)(17 + n) * CHSH;
    *(s16x8*)(dhi + tid * 16)     = *(const s16x8*)(hasm + tid * 16);
    *(s16x8*)(dhi + tid * 16 + 8) = *(const s16x8*)(hasm + tid * 16 + 8);
    *(s16x8*)(dlo + tid * 16)     = *(const s16x8*)(hasm + 4096 + tid * 16);
    *(s16x8*)(dlo + tid * 16 + 8) = *(const s16x8*)(hasm + 4096 + tid * 16 + 8);
}

extern "C" void kernel_launch(void* const* d_in, const int* in_sizes, int n_in,
                              void* d_out, int out_size, void* d_ws, size_t ws_size,
                              hipStream_t stream)
{
    float* out = (float*)d_out;
    if (ws_size < WS_NEED) { fill_out<<<512, 256, 0, stream>>>(out, 4000.f); return; }

    const float* input = (const float*)d_in[0];
    const float* mask  = (const float*)d_in[1];
    const float* biasm = (const float*)d_in[2];
    const float* w1    = (const float*)d_in[3];
    const float* b1    = (const float*)d_in[4];
    const float* cw    = (const float*)d_in[5];
    const float* cb    = (const float*)d_in[6];
    const float* w_ih  = (const float*)d_in[7];
    const float* w_hh  = (const float*)d_in[8];
    const float* b_ih  = (const float*)d_in[9];
    const float* b_hh  = (const float*)d_in[10];
    const float* fc1w  = (const float*)d_in[11];
    const float* fc1b  = (const float*)d_in[12];
    const float* c2w   = (const float*)d_in[13];
    const float* c2b   = (const float*)d_in[14];

    char* ws = (char*)d_ws;
    short* Wf = (short*)(ws + OFF_WF);
    short* A0 = (short*)(ws + OFF_AB);
    short* A1 = (short*)(ws + OFF_AB + AB_ONE);
    float* x    = (float*)(ws + OFF_X);
    float* ua   = (float*)(ws + OFF_UA);
    float* bsum = (float*)(ws + OFF_BS);
    float* accW = (float*)(ws + OFF_AC);
    float* accO = (float*)(ws + OFF_AC + ACC_HALF);
    float* cst  = (float*)(ws + OFF_CS);

    prep_x<<<(B_N * L_N) / 256, 256, 0, stream>>>(input, mask, w1, b1, cw, cb, x, ua);
    prep_wf<<<16 * CHA, 256, 0, stream>>>(w_ih, w_hh, Wf);
    prep_bs<<<(G_N + 255) / 256, 256, 0, stream>>>(b_ih, b_hh, bsum);
    prep_zero<<<(B_N * 1088 + 255) / 256, 256, 0, stream>>>((unsigned int*)A0, cst, accW);

    RParams P;
    P.mask = mask; P.bias_mat = biasm; P.fc1_w = fc1w; P.fc1_b = fc1b;
    P.conv2_w = c2w; P.conv2_b = c2b; P.Wf = Wf;
    P.x = x; P.ua = ua; P.bsum = bsum; P.accW = accW; P.accO = accO;
    P.cstate = cst; P.out = out;

    short* bufs[2] = { A0, A1 };
    for (int t = 0; t < T_N; ++t) {
        P.Ain  = bufs[t & 1];
        P.Aout = bufs[t & 1];
        ctx_step<<<B_N / 4, 256, 0, stream>>>(P, t);
        P.Ain  = bufs[t & 1];
        P.Aout = bufs[(t + 1) & 1];
        gemm_cell_step<<<512, 256, 0, stream>>>(P);
    }
    P.Ain = bufs[T_N & 1];
    P.Aout = bufs[T_N & 1];
    ctx_step<<<B_N / 4, 256, 0, stream>>>(P, T_N);
}

// Round 15
// 1240.278 us; speedup vs baseline: 1.8834x; 1.0990x over previous
//
#include <hip/hip_runtime.h>
#include <hip/hip_bf16.h>

#define B_N 4096
#define L_N 32
#define C_N 28
#define H_N 512
#define T_N 32
#define G_N 2048
// R15: full-fp16 GEMM. A (h/ctx) = fp16 hi/lo PAIR (chunks 0..16 hi, 17..33 lo;
// 2^-22 effective -- better than old bf16 pair). W = SINGLE fp16 (chunks 0..16;
// per-element err 2.4e-5 = 8x below R13's failing bf16 case 2e-4 -> predicted
// absmax ~0.02 via measured-calibrated linear scaling, threshold 0.068).
// Passes per chunk: Ah*W + Al*W = 32 MFMA (was 48); ds_read 12 (was 16);
// staging 24KB/step (was 32). mfma_f32_16x16x32_f16, same frag layout.
// W column packing: gate = t&3, unit = n128*32 + (t>>2)*16 + c (in-reg epilogue).
#define CHA 34
#define CHSH 4096          // shorts per frag chunk: 8 tiles * 64 lanes * 8
#define ABLK (CHA * CHSH)
#define XS 29              // padded LDS stride for prep_x

typedef __attribute__((ext_vector_type(2))) float f32x2;
typedef __attribute__((ext_vector_type(4))) float f32x4;
typedef __attribute__((ext_vector_type(8))) short s16x8;
typedef __attribute__((ext_vector_type(8))) _Float16 f16x8;

static constexpr size_t OFF_WF = 0;                                    // Wf f16 16*ABLK
static constexpr size_t AB_ONE = (size_t)32 * ABLK * 2;                // 8.9 MB
static constexpr size_t OFF_AB = OFF_WF + (size_t)16 * ABLK * 2;
static constexpr size_t OFF_X  = OFF_AB + 2 * AB_ONE;                  // f32 [4096][32][28]
static constexpr size_t OFF_UA = OFF_X + (size_t)B_N * L_N * C_N * 4;  // f32 [4096][32]
static constexpr size_t OFF_BS = OFF_UA + (size_t)B_N * L_N * 4;       // f32 [2048]
static constexpr size_t OFF_AC = OFF_BS + 8192;                        // accW[4096][32], accO[4096][32]
static constexpr size_t ACC_HALF = (size_t)32 * B_N * 4;               // 512 KB
static constexpr size_t OFF_CS = OFF_AC + 2 * ACC_HALF;                // f32 [4096][512]
static constexpr size_t WS_NEED = OFF_CS + (size_t)B_N * H_N * 4;      // ~36 MB

__device__ __forceinline__ short hfbits(float x) {
    union { _Float16 h; short s; } v; v.h = (_Float16)x; return v.s;
}
__device__ __forceinline__ float sigmoidf_(float x) { return 1.f / (1.f + __expf(-x)); }
__device__ __forceinline__ float tanhf_(float x) {
    float ax = fabsf(x), e = __expf(-2.f * ax);
    float t = (1.f - e) / (1.f + e);
    return x < 0.f ? -t : t;
}

__global__ __launch_bounds__(256) void fill_out(float* out, float v) {
    int i = blockIdx.x * 256 + threadIdx.x;
    if (i < B_N * 32) out[i] = v;
}

// ---------------- prep_x: x-in-registers + stencil shuffles + scalar weights ----------------
__global__ __launch_bounds__(256) void prep_x(const float* __restrict__ input,
                       const float* __restrict__ mask,
                       const float* __restrict__ w1, const float* __restrict__ b1,
                       const float* __restrict__ cw, const float* __restrict__ cb,
                       float* __restrict__ x, float* __restrict__ ua)
{
    __shared__ float sin[8 * L_N * XS];
    __shared__ float sxb[8 * L_N * XS];
    const float* src = input + (size_t)blockIdx.x * (8 * L_N * C_N);
    for (int i = threadIdx.x; i < 8 * L_N * C_N; i += 256) {
        int lr = i / (L_N * C_N);
        int rem = i - lr * (L_N * C_N);
        int l = rem / C_N, c = rem - l * C_N;
        sin[lr * (L_N * XS) + l * XS + c] = src[i];
    }
    __syncthreads();

    int idx = blockIdx.x * 256 + threadIdx.x;
    int l = idx & 31;
    int wv = threadIdx.x >> 5;
    const float* inb = sin + wv * (L_N * XS);
    float m = mask[idx];

    float x0r[C_N], xm1[C_N], xp1[C_N];
    #pragma unroll
    for (int i = 0; i < C_N; ++i) x0r[i] = inb[l * XS + i];
    #pragma unroll
    for (int i = 0; i < C_N; ++i) {
        float up = __shfl_up(x0r[i], 1, 32);
        float dn = __shfl_down(x0r[i], 1, 32);
        xm1[i] = (l > 0)  ? up : 0.f;
        xp1[i] = (l < 31) ? dn : 0.f;
    }

    float uacc = 0.f;
    float* sxrow = sxb + wv * (L_N * XS) + l * XS;
    #pragma unroll 2
    for (int o = 0; o < C_N; ++o) {
        const float* wo = w1 + o * (C_N * 3);   // wave-uniform -> s_load
        float y0 = b1[o], y1 = 0.f, y2 = 0.f;
        #pragma unroll
        for (int i = 0; i < C_N; ++i) {
            y0 += wo[i * 3 + 0] * xm1[i];
            y1 += wo[i * 3 + 1] * x0r[i];
            y2 += wo[i * 3 + 2] * xp1[i];
        }
        float y = (y0 + y1 + y2) * m;
        float e = (y > 0.f) ? y : (__expf(y) - 1.f);
        float xv = e + inb[l * XS + o];
        sxrow[o] = xv;
        uacc += xv * cw[o];
    }
    ua[idx] = (uacc + cb[0]) * m;
    __syncthreads();
    float* xdst = x + (size_t)blockIdx.x * (8 * L_N * C_N);
    for (int i = threadIdx.x; i < 8 * L_N * C_N; i += 256) {
        int lr = i / (L_N * C_N);
        int rem = i - lr * (L_N * C_N);
        int l2 = rem / C_N, c = rem - l2 * C_N;
        xdst[i] = sxb[lr * (L_N * XS) + l2 * XS + c];
    }
}

// ---------------- prep_wf: frag-major SINGLE-fp16 weights, gate-in-tile packing ----------------
__global__ __launch_bounds__(256) void prep_wf(const float* __restrict__ w_ih,
                                               const float* __restrict__ w_hh,
                                               short* __restrict__ Wf)
{
    int blk = blockIdx.x;                  // 16*17
    int n128 = blk / 17, c = blk % 17;
    int kbase = c * 32;
    short* dst = Wf + ((size_t)n128 * CHA + c) * CHSH;
    for (int g = threadIdx.x; g < 512; g += 256) {
        int j = g >> 6, lane = g & 63;
        int gate = j & 3;
        int unit = n128 * 32 + (j >> 2) * 16 + (lane & 15);
        int srow = gate * H_N + unit;
        int kg = lane >> 4;
        s16x8 out;
        #pragma unroll
        for (int b2 = 0; b2 < 8; ++b2) {
            int k = kbase + kg * 8 + b2;
            float v = 0.f;
            if (k < 512) v = w_hh[(size_t)srow * H_N + k];
            else if (k < 540) v = w_ih[srow * C_N + (k - 512)];
            out[b2] = hfbits(v);
        }
        *(s16x8*)(dst + g * 8) = out;
    }
}

__global__ void prep_bs(const float* __restrict__ b_ih, const float* __restrict__ b_hh,
                        float* __restrict__ bsum)
{
    int p = blockIdx.x * 256 + threadIdx.x;
    if (p < G_N) {
        int unit = p >> 2, gate = p & 3;
        bsum[p] = b_ih[gate * H_N + unit] + b_hh[gate * H_N + unit];
    }
}

__global__ void prep_zero(unsigned int* __restrict__ a32, float* __restrict__ cst,
                          float* __restrict__ acc)
{
    int idx = blockIdx.x * blockDim.x + threadIdx.x;
    if (idx < B_N * 1088) a32[idx] = 0u;
    if (idx < B_N * H_N) cst[idx] = 0.f;
    if (idx < 2 * 32 * B_N) acc[idx] = 0.f;
}

// ---------------- params ----------------
struct RParams {
    const float* mask;
    const float* bias_mat;
    const float* fc1_w;
    const float* fc1_b;
    const float* conv2_w;
    const float* conv2_b;
    const short* Wf;
    const short* Ain;
    short* Aout;
    const float* x;
    const float* ua;
    const float* bsum;
    float* accW;           // [4096][32] slot = n*2+wn
    float* accO;           // [4096][32]
    float* cstate;
    float* out;
};

// ---------------- ctx_step: sum 32 partial slots; softmax+context (LDS-staged x) ----------------
__global__ __launch_bounds__(256) void ctx_step(RParams P, int t)
{
    __shared__ float sx[4][L_N * C_N];

    const int lane = threadIdx.x & 63;
    const int wave = threadIdx.x >> 6;
    const int row  = blockIdx.x * 4 + wave;

    f32x2 st[7];
    const float* xrow = P.x + (size_t)row * (L_N * C_N);
    #pragma unroll
    for (int q = 0; q < 7; ++q) st[q] = *(const f32x2*)(xrow + (q * 64 + lane) * 2);

    float v = (lane < 32) ? P.accW[row * 32 + lane] : P.accO[row * 32 + (lane - 32)];
    #pragma unroll
    for (int off = 1; off <= 16; off <<= 1) v += __shfl_xor(v, off);
    float aW = __shfl(v, 0);
    float aO = __shfl(v, 32);

    if (t > 0 && lane == 0)
        P.out[row * T_N + (t - 1)] = (aO + P.conv2_b[0]) * P.mask[row * L_N + (t - 1)];

    if (t < T_N) {
        float w_a = aW + P.fc1_b[0];
        int l32 = lane & 31;
        float e = P.ua[row * L_N + l32] + w_a;
        e = (e > 0.f) ? e : 0.01f * e;
        e += P.bias_mat[row * L_N + l32];
        float mx = e;
        #pragma unroll
        for (int off = 16; off > 0; off >>= 1) mx = fmaxf(mx, __shfl_xor(mx, off, 32));
        float pexp = __expf(e - mx);
        float ssum = pexp;
        #pragma unroll
        for (int off = 16; off > 0; off >>= 1) ssum += __shfl_xor(ssum, off, 32);
        float p = pexp / ssum;

        #pragma unroll
        for (int q = 0; q < 7; ++q)
            *(f32x2*)(&sx[wave][(q * 64 + lane) * 2]) = st[q];

        int cc = (lane < C_N) ? lane : 0;
        float ctx = 0.f;
        #pragma unroll
        for (int l = 0; l < L_N; ++l) {
            float al = __shfl(p, l);
            ctx += al * sx[wave][l * C_N + cc];
        }
        if (lane < C_N) {
            int m128 = row >> 7, mt = (row & 127) >> 4, r = row & 15;
            int flane = r + 16 * (lane >> 3);
            short* base = P.Aout + (size_t)m128 * ABLK + mt * 512 + flane * 8 + (lane & 7);
            _Float16 hi = (_Float16)ctx;
            union { _Float16 h; short s; } uh; uh.h = hi;
            base[16 * CHSH] = uh.s;
            base[33 * CHSH] = hfbits(ctx - (float)hi);
        }
    }
}

// ---------------- gemm_cell_step: M=128, 24KB dbuf (fp16: A-pair, W-single), SGB ----------------
// Buffer (24KB): [A_hi 8K | A_lo 8K | W 8K] = 24 rows x 1KB; each wave stages 6
// uniform rows. Per step: 6 VMEM + 12 DS_READ + 32 MFMA f16 (Ah*W, Al*W).
#define STG_BUF 24576

__global__ __launch_bounds__(256, 2) void gemm_cell_step(RParams P)
{
    __shared__ __align__(16) char smem[49152];

    const int tid  = threadIdx.x;
    const int lane = tid & 63;
    const int wave = tid >> 6;
    const int bid  = blockIdx.x;       // 512
    const int xg = bid & 7, gg = bid >> 3;
    const int m  = (xg >> 1) * 8 + (gg & 7);
    const int n  = (xg & 1) * 8 + (gg >> 3);
    const int wm = wave >> 1, wn = wave & 1;

    const short* Af = P.Ain + (size_t)m * ABLK;
    const short* Wg = P.Wf  + (size_t)n * ABLK;

    char* bufp0 = smem;
    char* bufp1 = smem + STG_BUF;

    auto stage = [&](char* lbuf, int kk) {
        const short* pAh = Af + (size_t)kk * CHSH;
        const short* pAl = Af + (size_t)(17 + kk) * CHSH;
        const short* pW  = Wg + (size_t)kk * CHSH;
        #pragma unroll
        for (int i = 0; i < 6; ++i) {
            int r = wave * 6 + i;
            const short* base = (r < 8)  ? (pAh + r * 512)
                              : (r < 16) ? (pAl + (r - 8) * 512)
                                         : (pW + (r - 16) * 512);
            __builtin_amdgcn_global_load_lds(
                (const __attribute__((address_space(1))) void*)(base + lane * 8),
                (__attribute__((address_space(3))) void*)(lbuf + r * 1024),
                16, 0, 0);
        }
    };

    int aoff[4], woff[4];
    #pragma unroll
    for (int i = 0; i < 4; ++i) {
        aoff[i] = ((wm * 4 + i) * 64 + lane) * 16;
        woff[i] = ((wn * 4 + i) * 64 + lane) * 16;
    }

    f32x4 acc[4][4];
    #pragma unroll
    for (int i = 0; i < 4; ++i)
        #pragma unroll
        for (int j = 0; j < 4; ++j)
            acc[i][j] = (f32x4){0.f, 0.f, 0.f, 0.f};

    // R[0..3]=A_hi, R[4..7]=A_lo, R[8..11]=W
    f16x8 RA[12], RB[12];
    auto ldfr = [&](const char* b, f16x8 (&R)[12]) {
        #pragma unroll
        for (int i = 0; i < 4; ++i) {
            R[i]     = *(const f16x8*)(b + aoff[i]);
            R[4 + i] = *(const f16x8*)(b + 8192 + aoff[i]);
            R[8 + i] = *(const f16x8*)(b + 16384 + woff[i]);
        }
    };
    auto domm = [&](f16x8 (&R)[12]) {
        #pragma unroll
        for (int i = 0; i < 4; ++i)
            #pragma unroll
            for (int j = 0; j < 4; ++j)
                acc[i][j] = __builtin_amdgcn_mfma_f32_16x16x32_f16(R[i], R[8 + j], acc[i][j], 0, 0, 0);
        #pragma unroll
        for (int i = 0; i < 4; ++i)
            #pragma unroll
            for (int j = 0; j < 4; ++j)
                acc[i][j] = __builtin_amdgcn_mfma_f32_16x16x32_f16(R[4 + i], R[8 + j], acc[i][j], 0, 0, 0);
    };

    // full step: 6 VMEM (stage) + 12 DS_READ (prefetch) + 32 MFMA, SGB-interleaved
    auto step_full = [&](int kk, f16x8 (&Rc)[12], f16x8 (&Rn)[12], char* bcur, char* bnext) {
        asm volatile("s_waitcnt vmcnt(0) lgkmcnt(0)" ::: "memory");
        __builtin_amdgcn_s_barrier();
        __builtin_amdgcn_sched_barrier(0);
        stage(bcur, kk + 2);
        ldfr(bnext, Rn);
        domm(Rc);
        #pragma unroll
        for (int g = 0; g < 6; ++g) {
            __builtin_amdgcn_sched_group_barrier(0x010, 1, 0);  // 1 VMEM (global_load_lds)
            __builtin_amdgcn_sched_group_barrier(0x100, 2, 0);  // 2 DS_READ
            __builtin_amdgcn_sched_group_barrier(0x008, 5, 0);  // 5 MFMA
        }
        __builtin_amdgcn_sched_group_barrier(0x008, 2, 0);      // remaining 2 MFMA
        __builtin_amdgcn_sched_barrier(0);
    };
    // no-stage step (kk==15): 12 DS_READ + 32 MFMA
    auto step_nos = [&](f16x8 (&Rc)[12], f16x8 (&Rn)[12], char* bnext) {
        asm volatile("s_waitcnt vmcnt(0) lgkmcnt(0)" ::: "memory");
        __builtin_amdgcn_s_barrier();
        __builtin_amdgcn_sched_barrier(0);
        ldfr(bnext, Rn);
        domm(Rc);
        #pragma unroll
        for (int g = 0; g < 6; ++g) {
            __builtin_amdgcn_sched_group_barrier(0x100, 2, 0);
            __builtin_amdgcn_sched_group_barrier(0x008, 5, 0);
        }
        __builtin_amdgcn_sched_group_barrier(0x008, 2, 0);
        __builtin_amdgcn_sched_barrier(0);
    };
    // last step (kk==16): MFMA only
    auto step_last = [&](f16x8 (&Rc)[12]) {
        asm volatile("s_waitcnt vmcnt(0) lgkmcnt(0)" ::: "memory");
        __builtin_amdgcn_s_barrier();
        __builtin_amdgcn_sched_barrier(0);
        domm(Rc);
        __builtin_amdgcn_sched_barrier(0);
    };

    stage(bufp0, 0);
    asm volatile("s_waitcnt vmcnt(0)" ::: "memory");
    __builtin_amdgcn_s_barrier();
    stage(bufp1, 1);
    ldfr(bufp0, RA);

    for (int kp = 0; kp < 7; ++kp) {
        step_full(2 * kp,     RA, RB, bufp0, bufp1);
        step_full(2 * kp + 1, RB, RA, bufp1, bufp0);
    }
    step_full(14, RA, RB, bufp0, bufp1);   // stages chunk 16 into bufp0
    step_nos(RB, RA, bufp0);               // kk=15: ldfr chunk 16 from bufp0
    step_last(RA);                         // kk=16

    // ---- epilogue (in-register LSTM: thread owns unit = n*32+wn*16+(lane&15)) ----
    __syncthreads();
    short* hasm = (short*)smem;              // hi 8KB @0, lo 8KB @8192
    {
        int u15 = lane & 15, rq = lane >> 4;
        int unit = n * 32 + wn * 16 + u15;
        float cpre[4][4];
        #pragma unroll
        for (int i = 0; i < 4; ++i)
            #pragma unroll
            for (int r = 0; r < 4; ++r)
                cpre[i][r] = P.cstate[(size_t)(m * 128 + wm * 64 + i * 16 + rq * 4 + r) * H_N + unit];
        f32x4 bsv = *(const f32x4*)(P.bsum + unit * 4);
        float f1v = P.fc1_w[unit];
        float c2v = P.conv2_w[unit];
        const int fl16 = 16 * (wn * 2 + (u15 >> 3));
        const int slot = u15 & 7;
        #pragma unroll
        for (int i = 0; i < 4; ++i) {
            #pragma unroll
            for (int r = 0; r < 4; ++r) {
                int grow = m * 128 + wm * 64 + i * 16 + rq * 4 + r;
                float pi = acc[i][0][r] + bsv.x;
                float pf = acc[i][1][r] + bsv.y;
                float pg = acc[i][2][r] + bsv.z;
                float po = acc[i][3][r] + bsv.w;
                float c = sigmoidf_(pf) * cpre[i][r] + sigmoidf_(pi) * tanhf_(pg);
                P.cstate[(size_t)grow * H_N + unit] = c;
                float h = sigmoidf_(po) * tanhf_(c);
                _Float16 hh = (_Float16)h;
                union { _Float16 hf; short s; } uh; uh.hf = hh;
                int fo = (wm * 4 + i) * 512 + (rq * 4 + r + fl16) * 8 + slot;
                hasm[fo]        = uh.s;
                hasm[4096 + fo] = hfbits(h - (float)hh);
                float wd = f1v * h, od = c2v * h;
                #pragma unroll
                for (int off = 8; off > 0; off >>= 1) {
                    wd += __shfl_xor(wd, off);
                    od += __shfl_xor(od, off);
                }
                if (u15 == 0) {
                    P.accW[(size_t)grow * 32 + (n * 2 + wn)] = wd;
                    P.accO[(size_t)grow * 32 + (n * 2 + wn)] = od;
                }
            }
        }
    }
    __syncthreads();
    short* dhi = P.Aout + (size_t)m * ABLK + (size_t)n * CHSH;
    short* dlo = P.Aout + (size_t)m * ABLK + (size_t)(17 + n) * CHSH;
    *(s16x8*)(dhi + tid * 16)     = *(const s16x8*)(hasm + tid * 16);
    *(s16x8*)(dhi + tid * 16 + 8) = *(const s16x8*)(hasm + tid * 16 + 8);
    *(s16x8*)(dlo + tid * 16)     = *(const s16x8*)(hasm + 4096 + tid * 16);
    *(s16x8*)(dlo + tid * 16 + 8) = *(const s16x8*)(hasm + 4096 + tid * 16 + 8);
}

extern "C" void kernel_launch(void* const* d_in, const int* in_sizes, int n_in,
                              void* d_out, int out_size, void* d_ws, size_t ws_size,
                              hipStream_t stream)
{
    float* out = (float*)d_out;
    if (ws_size < WS_NEED) { fill_out<<<512, 256, 0, stream>>>(out, 4000.f); return; }

    const float* input = (const float*)d_in[0];
    const float* mask  = (const float*)d_in[1];
    const float* biasm = (const float*)d_in[2];
    const float* w1    = (const float*)d_in[3];
    const float* b1    = (const float*)d_in[4];
    const float* cw    = (const float*)d_in[5];
    const float* cb    = (const float*)d_in[6];
    const float* w_ih  = (const float*)d_in[7];
    const float* w_hh  = (const float*)d_in[8];
    const float* b_ih  = (const float*)d_in[9];
    const float* b_hh  = (const float*)d_in[10];
    const float* fc1w  = (const float*)d_in[11];
    const float* fc1b  = (const float*)d_in[12];
    const float* c2w   = (const float*)d_in[13];
    const float* c2b   = (const float*)d_in[14];

    char* ws = (char*)d_ws;
    short* Wf = (short*)(ws + OFF_WF);
    short* A0 = (short*)(ws + OFF_AB);
    short* A1 = (short*)(ws + OFF_AB + AB_ONE);
    float* x    = (float*)(ws + OFF_X);
    float* ua   = (float*)(ws + OFF_UA);
    float* bsum = (float*)(ws + OFF_BS);
    float* accW = (float*)(ws + OFF_AC);
    float* accO = (float*)(ws + OFF_AC + ACC_HALF);
    float* cst  = (float*)(ws + OFF_CS);

    prep_x<<<(B_N * L_N) / 256, 256, 0, stream>>>(input, mask, w1, b1, cw, cb, x, ua);
    prep_wf<<<16 * 17, 256, 0, stream>>>(w_ih, w_hh, Wf);
    prep_bs<<<(G_N + 255) / 256, 256, 0, stream>>>(b_ih, b_hh, bsum);
    prep_zero<<<(B_N * 1088 + 255) / 256, 256, 0, stream>>>((unsigned int*)A0, cst, accW);

    RParams P;
    P.mask = mask; P.bias_mat = biasm; P.fc1_w = fc1w; P.fc1_b = fc1b;
    P.conv2_w = c2w; P.conv2_b = c2b; P.Wf = Wf;
    P.x = x; P.ua = ua; P.bsum = bsum; P.accW = accW; P.accO = accO;
    P.cstate = cst; P.out = out;

    short* bufs[2] = { A0, A1 };
    for (int t = 0; t < T_N; ++t) {
        P.Ain  = bufs[t & 1];
        P.Aout = bufs[t & 1];
        ctx_step<<<B_N / 4, 256, 0, stream>>>(P, t);
        P.Ain  = bufs[t & 1];
        P.Aout = bufs[(t + 1) & 1];
        gemm_cell_step<<<512, 256, 0, stream>>>(P);
    }
    P.Ain = bufs[T_N & 1];
    P.Aout = bufs[T_N & 1];
    ctx_step<<<B_N / 4, 256, 0, stream>>>(P, T_N);
}

// Round 16
// 1225.532 us; speedup vs baseline: 1.9061x; 1.0120x over previous
//
#include <hip/hip_runtime.h>
#include <hip/hip_bf16.h>

#define B_N 4096
#define L_N 32
#define C_N 28
#define H_N 512
#define T_N 32
#define G_N 2048
// R16 = R15 numerics (fp16: A hi/lo pair, W single) + paired k-steps.
// K layout: A chunks [0..16]=hi, [17..33]=lo; W chunks [0..16] single fp16.
// Per step: TWO chunks (bufp0=even, bufp1=odd); phase1 = 24 ds_read,
// phase2 = stage next pair + 64 MFMA (SGB-interleaved). 9 steps (was 17)
// -> sync points halved. Summation order identical to R15 (sequential chunks).
// W column packing: gate = t&3, unit = n128*32 + (t>>2)*16 + c (in-reg epilogue).
#define CHA 34
#define CHSH 4096          // shorts per frag chunk: 8 tiles * 64 lanes * 8
#define ABLK (CHA * CHSH)
#define XS 29              // padded LDS stride for prep_x

typedef __attribute__((ext_vector_type(2))) float f32x2;
typedef __attribute__((ext_vector_type(4))) float f32x4;
typedef __attribute__((ext_vector_type(8))) short s16x8;
typedef __attribute__((ext_vector_type(8))) _Float16 f16x8;

static constexpr size_t OFF_WF = 0;                                    // Wf f16 16*ABLK
static constexpr size_t AB_ONE = (size_t)32 * ABLK * 2;                // 8.9 MB
static constexpr size_t OFF_AB = OFF_WF + (size_t)16 * ABLK * 2;
static constexpr size_t OFF_X  = OFF_AB + 2 * AB_ONE;                  // f32 [4096][32][28]
static constexpr size_t OFF_UA = OFF_X + (size_t)B_N * L_N * C_N * 4;  // f32 [4096][32]
static constexpr size_t OFF_BS = OFF_UA + (size_t)B_N * L_N * 4;       // f32 [2048]
static constexpr size_t OFF_AC = OFF_BS + 8192;                        // accW[4096][32], accO[4096][32]
static constexpr size_t ACC_HALF = (size_t)32 * B_N * 4;               // 512 KB
static constexpr size_t OFF_CS = OFF_AC + 2 * ACC_HALF;                // f32 [4096][512]
static constexpr size_t WS_NEED = OFF_CS + (size_t)B_N * H_N * 4;      // ~36 MB

__device__ __forceinline__ short hfbits(float x) {
    union { _Float16 h; short s; } v; v.h = (_Float16)x; return v.s;
}
__device__ __forceinline__ float sigmoidf_(float x) { return 1.f / (1.f + __expf(-x)); }
__device__ __forceinline__ float tanhf_(float x) {
    float ax = fabsf(x), e = __expf(-2.f * ax);
    float t = (1.f - e) / (1.f + e);
    return x < 0.f ? -t : t;
}

__global__ __launch_bounds__(256) void fill_out(float* out, float v) {
    int i = blockIdx.x * 256 + threadIdx.x;
    if (i < B_N * 32) out[i] = v;
}

// ---------------- prep_x: x-in-registers + stencil shuffles + scalar weights ----------------
__global__ __launch_bounds__(256) void prep_x(const float* __restrict__ input,
                       const float* __restrict__ mask,
                       const float* __restrict__ w1, const float* __restrict__ b1,
                       const float* __restrict__ cw, const float* __restrict__ cb,
                       float* __restrict__ x, float* __restrict__ ua)
{
    __shared__ float sin[8 * L_N * XS];
    __shared__ float sxb[8 * L_N * XS];
    const float* src = input + (size_t)blockIdx.x * (8 * L_N * C_N);
    for (int i = threadIdx.x; i < 8 * L_N * C_N; i += 256) {
        int lr = i / (L_N * C_N);
        int rem = i - lr * (L_N * C_N);
        int l = rem / C_N, c = rem - l * C_N;
        sin[lr * (L_N * XS) + l * XS + c] = src[i];
    }
    __syncthreads();

    int idx = blockIdx.x * 256 + threadIdx.x;
    int l = idx & 31;
    int wv = threadIdx.x >> 5;
    const float* inb = sin + wv * (L_N * XS);
    float m = mask[idx];

    float x0r[C_N], xm1[C_N], xp1[C_N];
    #pragma unroll
    for (int i = 0; i < C_N; ++i) x0r[i] = inb[l * XS + i];
    #pragma unroll
    for (int i = 0; i < C_N; ++i) {
        float up = __shfl_up(x0r[i], 1, 32);
        float dn = __shfl_down(x0r[i], 1, 32);
        xm1[i] = (l > 0)  ? up : 0.f;
        xp1[i] = (l < 31) ? dn : 0.f;
    }

    float uacc = 0.f;
    float* sxrow = sxb + wv * (L_N * XS) + l * XS;
    #pragma unroll 2
    for (int o = 0; o < C_N; ++o) {
        const float* wo = w1 + o * (C_N * 3);   // wave-uniform -> s_load
        float y0 = b1[o], y1 = 0.f, y2 = 0.f;
        #pragma unroll
        for (int i = 0; i < C_N; ++i) {
            y0 += wo[i * 3 + 0] * xm1[i];
            y1 += wo[i * 3 + 1] * x0r[i];
            y2 += wo[i * 3 + 2] * xp1[i];
        }
        float y = (y0 + y1 + y2) * m;
        float e = (y > 0.f) ? y : (__expf(y) - 1.f);
        float xv = e + inb[l * XS + o];
        sxrow[o] = xv;
        uacc += xv * cw[o];
    }
    ua[idx] = (uacc + cb[0]) * m;
    __syncthreads();
    float* xdst = x + (size_t)blockIdx.x * (8 * L_N * C_N);
    for (int i = threadIdx.x; i < 8 * L_N * C_N; i += 256) {
        int lr = i / (L_N * C_N);
        int rem = i - lr * (L_N * C_N);
        int l2 = rem / C_N, c = rem - l2 * C_N;
        xdst[i] = sxb[lr * (L_N * XS) + l2 * XS + c];
    }
}

// ---------------- prep_wf: frag-major SINGLE-fp16 weights, gate-in-tile packing ----------------
__global__ __launch_bounds__(256) void prep_wf(const float* __restrict__ w_ih,
                                               const float* __restrict__ w_hh,
                                               short* __restrict__ Wf)
{
    int blk = blockIdx.x;                  // 16*17
    int n128 = blk / 17, c = blk % 17;
    int kbase = c * 32;
    short* dst = Wf + ((size_t)n128 * CHA + c) * CHSH;
    for (int g = threadIdx.x; g < 512; g += 256) {
        int j = g >> 6, lane = g & 63;
        int gate = j & 3;
        int unit = n128 * 32 + (j >> 2) * 16 + (lane & 15);
        int srow = gate * H_N + unit;
        int kg = lane >> 4;
        s16x8 out;
        #pragma unroll
        for (int b2 = 0; b2 < 8; ++b2) {
            int k = kbase + kg * 8 + b2;
            float v = 0.f;
            if (k < 512) v = w_hh[(size_t)srow * H_N + k];
            else if (k < 540) v = w_ih[srow * C_N + (k - 512)];
            out[b2] = hfbits(v);
        }
        *(s16x8*)(dst + g * 8) = out;
    }
}

__global__ void prep_bs(const float* __restrict__ b_ih, const float* __restrict__ b_hh,
                        float* __restrict__ bsum)
{
    int p = blockIdx.x * 256 + threadIdx.x;
    if (p < G_N) {
        int unit = p >> 2, gate = p & 3;
        bsum[p] = b_ih[gate * H_N + unit] + b_hh[gate * H_N + unit];
    }
}

__global__ void prep_zero(unsigned int* __restrict__ a32, float* __restrict__ cst,
                          float* __restrict__ acc)
{
    int idx = blockIdx.x * blockDim.x + threadIdx.x;
    if (idx < B_N * 1088) a32[idx] = 0u;
    if (idx < B_N * H_N) cst[idx] = 0.f;
    if (idx < 2 * 32 * B_N) acc[idx] = 0.f;
}

// ---------------- params ----------------
struct RParams {
    const float* mask;
    const float* bias_mat;
    const float* fc1_w;
    const float* fc1_b;
    const float* conv2_w;
    const float* conv2_b;
    const short* Wf;
    const short* Ain;
    short* Aout;
    const float* x;
    const float* ua;
    const float* bsum;
    float* accW;           // [4096][32] slot = n*2+wn
    float* accO;           // [4096][32]
    float* cstate;
    float* out;
};

// ---------------- ctx_step: sum 32 partial slots; softmax+context (LDS-staged x) ----------------
__global__ __launch_bounds__(256) void ctx_step(RParams P, int t)
{
    __shared__ float sx[4][L_N * C_N];

    const int lane = threadIdx.x & 63;
    const int wave = threadIdx.x >> 6;
    const int row  = blockIdx.x * 4 + wave;

    f32x2 st[7];
    const float* xrow = P.x + (size_t)row * (L_N * C_N);
    #pragma unroll
    for (int q = 0; q < 7; ++q) st[q] = *(const f32x2*)(xrow + (q * 64 + lane) * 2);

    float v = (lane < 32) ? P.accW[row * 32 + lane] : P.accO[row * 32 + (lane - 32)];
    #pragma unroll
    for (int off = 1; off <= 16; off <<= 1) v += __shfl_xor(v, off);
    float aW = __shfl(v, 0);
    float aO = __shfl(v, 32);

    if (t > 0 && lane == 0)
        P.out[row * T_N + (t - 1)] = (aO + P.conv2_b[0]) * P.mask[row * L_N + (t - 1)];

    if (t < T_N) {
        float w_a = aW + P.fc1_b[0];
        int l32 = lane & 31;
        float e = P.ua[row * L_N + l32] + w_a;
        e = (e > 0.f) ? e : 0.01f * e;
        e += P.bias_mat[row * L_N + l32];
        float mx = e;
        #pragma unroll
        for (int off = 16; off > 0; off >>= 1) mx = fmaxf(mx, __shfl_xor(mx, off, 32));
        float pexp = __expf(e - mx);
        float ssum = pexp;
        #pragma unroll
        for (int off = 16; off > 0; off >>= 1) ssum += __shfl_xor(ssum, off, 32);
        float p = pexp / ssum;

        #pragma unroll
        for (int q = 0; q < 7; ++q)
            *(f32x2*)(&sx[wave][(q * 64 + lane) * 2]) = st[q];

        int cc = (lane < C_N) ? lane : 0;
        float ctx = 0.f;
        #pragma unroll
        for (int l = 0; l < L_N; ++l) {
            float al = __shfl(p, l);
            ctx += al * sx[wave][l * C_N + cc];
        }
        if (lane < C_N) {
            int m128 = row >> 7, mt = (row & 127) >> 4, r = row & 15;
            int flane = r + 16 * (lane >> 3);
            short* base = P.Aout + (size_t)m128 * ABLK + mt * 512 + flane * 8 + (lane & 7);
            _Float16 hi = (_Float16)ctx;
            union { _Float16 h; short s; } uh; uh.h = hi;
            base[16 * CHSH] = uh.s;
            base[33 * CHSH] = hfbits(ctx - (float)hi);
        }
    }
}

// ---------------- gemm_cell_step: M=128, paired k-steps, fp16, SGB ----------------
// Buffer (24KB): [A_hi 8K | A_lo 8K | W 8K]; bufp0=even chunks, bufp1=odd.
// Step: vmcnt(0)+bar -> 24 ds_read -> lgkmcnt(0)+bar -> stage next pair + 64 MFMA.
#define STG_BUF 24576

__global__ __launch_bounds__(256, 2) void gemm_cell_step(RParams P)
{
    __shared__ __align__(16) char smem[49152];

    const int tid  = threadIdx.x;
    const int lane = tid & 63;
    const int wave = tid >> 6;
    const int bid  = blockIdx.x;       // 512
    const int xg = bid & 7, gg = bid >> 3;
    const int m  = (xg >> 1) * 8 + (gg & 7);
    const int n  = (xg & 1) * 8 + (gg >> 3);
    const int wm = wave >> 1, wn = wave & 1;

    const short* Af = P.Ain + (size_t)m * ABLK;
    const short* Wg = P.Wf  + (size_t)n * ABLK;

    char* bufp0 = smem;
    char* bufp1 = smem + STG_BUF;

    auto stage = [&](char* lbuf, int kk) {
        const short* pAh = Af + (size_t)kk * CHSH;
        const short* pAl = Af + (size_t)(17 + kk) * CHSH;
        const short* pW  = Wg + (size_t)kk * CHSH;
        #pragma unroll
        for (int i = 0; i < 6; ++i) {
            int r = wave * 6 + i;
            const short* base = (r < 8)  ? (pAh + r * 512)
                              : (r < 16) ? (pAl + (r - 8) * 512)
                                         : (pW + (r - 16) * 512);
            __builtin_amdgcn_global_load_lds(
                (const __attribute__((address_space(1))) void*)(base + lane * 8),
                (__attribute__((address_space(3))) void*)(lbuf + r * 1024),
                16, 0, 0);
        }
    };

    int aoff[4], woff[4];
    #pragma unroll
    for (int i = 0; i < 4; ++i) {
        aoff[i] = ((wm * 4 + i) * 64 + lane) * 16;
        woff[i] = ((wn * 4 + i) * 64 + lane) * 16;
    }

    f32x4 acc[4][4];
    #pragma unroll
    for (int i = 0; i < 4; ++i)
        #pragma unroll
        for (int j = 0; j < 4; ++j)
            acc[i][j] = (f32x4){0.f, 0.f, 0.f, 0.f};

    // R[0..3]=A_hi, R[4..7]=A_lo, R[8..11]=W
    f16x8 R0[12], R1[12];
    auto ldfr = [&](const char* b, f16x8 (&R)[12]) {
        #pragma unroll
        for (int i = 0; i < 4; ++i) {
            R[i]     = *(const f16x8*)(b + aoff[i]);
            R[4 + i] = *(const f16x8*)(b + 8192 + aoff[i]);
            R[8 + i] = *(const f16x8*)(b + 16384 + woff[i]);
        }
    };
    auto domm = [&](f16x8 (&R)[12]) {
        #pragma unroll
        for (int i = 0; i < 4; ++i)
            #pragma unroll
            for (int j = 0; j < 4; ++j)
                acc[i][j] = __builtin_amdgcn_mfma_f32_16x16x32_f16(R[i], R[8 + j], acc[i][j], 0, 0, 0);
        #pragma unroll
        for (int i = 0; i < 4; ++i)
            #pragma unroll
            for (int j = 0; j < 4; ++j)
                acc[i][j] = __builtin_amdgcn_mfma_f32_16x16x32_f16(R[4 + i], R[8 + j], acc[i][j], 0, 0, 0);
    };

    // paired step: phase1 = 24 ds_read (both buffers); phase2 = stage next pair
    // (12 or 6 VMEM) interleaved with 64 MFMA via SGB. nstage: 2, 1, or 0.
    auto step_pair = [&](int c0, int nstage) {
        asm volatile("s_waitcnt vmcnt(0) lgkmcnt(0)" ::: "memory");
        __builtin_amdgcn_s_barrier();
        __builtin_amdgcn_sched_barrier(0);
        ldfr(bufp0, R0);
        ldfr(bufp1, R1);
        asm volatile("s_waitcnt lgkmcnt(0)" ::: "memory");
        __builtin_amdgcn_sched_barrier(0);       // rule #18: reads sealed here
        __builtin_amdgcn_s_barrier();            // all waves' reads done -> overwrite ok
        __builtin_amdgcn_sched_barrier(0);
        if (nstage >= 1) stage(bufp0, c0 + 2);
        if (nstage >= 2) stage(bufp1, c0 + 3);
        domm(R0);
        domm(R1);
        if (nstage == 2) {
            #pragma unroll
            for (int g = 0; g < 12; ++g) {
                __builtin_amdgcn_sched_group_barrier(0x010, 1, 0);  // 1 VMEM
                __builtin_amdgcn_sched_group_barrier(0x008, 5, 0);  // 5 MFMA
            }
            __builtin_amdgcn_sched_group_barrier(0x008, 4, 0);      // remaining 4
        } else if (nstage == 1) {
            #pragma unroll
            for (int g = 0; g < 6; ++g) {
                __builtin_amdgcn_sched_group_barrier(0x010, 1, 0);
                __builtin_amdgcn_sched_group_barrier(0x008, 8, 0);
            }
            __builtin_amdgcn_sched_group_barrier(0x008, 16, 0);
        }
        __builtin_amdgcn_sched_barrier(0);
    };
    // final single chunk (16) from bufp0
    auto step_single = [&]() {
        asm volatile("s_waitcnt vmcnt(0) lgkmcnt(0)" ::: "memory");
        __builtin_amdgcn_s_barrier();
        __builtin_amdgcn_sched_barrier(0);
        ldfr(bufp0, R0);
        domm(R0);
        __builtin_amdgcn_sched_barrier(0);
    };

    stage(bufp0, 0);
    stage(bufp1, 1);

    for (int s = 0; s < 7; ++s)
        step_pair(2 * s, 2);          // chunks 0..13, stage 2..15
    step_pair(14, 1);                 // chunks 14,15; stage chunk 16 -> bufp0
    step_single();                    // chunk 16

    // ---- epilogue (in-register LSTM: thread owns unit = n*32+wn*16+(lane&15)) ----
    __syncthreads();
    short* hasm = (short*)smem;              // hi 8KB @0, lo 8KB @8192
    {
        int u15 = lane & 15, rq = lane >> 4;
        int unit = n * 32 + wn * 16 + u15;
        float cpre[4][4];
        #pragma unroll
        for (int i = 0; i < 4; ++i)
            #pragma unroll
            for (int r = 0; r < 4; ++r)
                cpre[i][r] = P.cstate[(size_t)(m * 128 + wm * 64 + i * 16 + rq * 4 + r) * H_N + unit];
        f32x4 bsv = *(const f32x4*)(P.bsum + unit * 4);
        float f1v = P.fc1_w[unit];
        float c2v = P.conv2_w[unit];
        const int fl16 = 16 * (wn * 2 + (u15 >> 3));
        const int slot = u15 & 7;
        #pragma unroll
        for (int i = 0; i < 4; ++i) {
            #pragma unroll
            for (int r = 0; r < 4; ++r) {
                int grow = m * 128 + wm * 64 + i * 16 + rq * 4 + r;
                float pi = acc[i][0][r] + bsv.x;
                float pf = acc[i][1][r] + bsv.y;
                float pg = acc[i][2][r] + bsv.z;
                float po = acc[i][3][r] + bsv.w;
                float c = sigmoidf_(pf) * cpre[i][r] + sigmoidf_(pi) * tanhf_(pg);
                P.cstate[(size_t)grow * H_N + unit] = c;
                float h = sigmoidf_(po) * tanhf_(c);
                _Float16 hh = (_Float16)h;
                union { _Float16 hf; short s; } uh; uh.hf = hh;
                int fo = (wm * 4 + i) * 512 + (rq * 4 + r + fl16) * 8 + slot;
                hasm[fo]        = uh.s;
                hasm[4096 + fo] = hfbits(h - (float)hh);
                float wd = f1v * h, od = c2v * h;
                #pragma unroll
                for (int off = 8; off > 0; off >>= 1) {
                    wd += __shfl_xor(wd, off);
                    od += __shfl_xor(od, off);
                }
                if (u15 == 0) {
                    P.accW[(size_t)grow * 32 + (n * 2 + wn)] = wd;
                    P.accO[(size_t)grow * 32 + (n * 2 + wn)] = od;
                }
            }
        }
    }
    __syncthreads();
    short* dhi = P.Aout + (size_t)m * ABLK + (size_t)n * CHSH;
    short* dlo = P.Aout + (size_t)m * ABLK + (size_t)(17 + n) * CHSH;
    *(s16x8*)(dhi + tid * 16)     = *(const s16x8*)(hasm + tid * 16);
    *(s16x8*)(dhi + tid * 16 + 8) = *(const s16x8*)(hasm + tid * 16 + 8);
    *(s16x8*)(dlo + tid * 16)     = *(const s16x8*)(hasm + 4096 + tid * 16);
    *(s16x8*)(dlo + tid * 16 + 8) = *(const s16x8*)(hasm + 4096 + tid * 16 + 8);
}

extern "C" void kernel_launch(void* const* d_in, const int* in_sizes, int n_in,
                              void* d_out, int out_size, void* d_ws, size_t ws_size,
                              hipStream_t stream)
{
    float* out = (float*)d_out;
    if (ws_size < WS_NEED) { fill_out<<<512, 256, 0, stream>>>(out, 4000.f); return; }

    const float* input = (const float*)d_in[0];
    const float* mask  = (const float*)d_in[1];
    const float* biasm = (const float*)d_in[2];
    const float* w1    = (const float*)d_in[3];
    const float* b1    = (const float*)d_in[4];
    const float* cw    = (const float*)d_in[5];
    const float* cb    = (const float*)d_in[6];
    const float* w_ih  = (const float*)d_in[7];
    const float* w_hh  = (const float*)d_in[8];
    const float* b_ih  = (const float*)d_in[9];
    const float* b_hh  = (const float*)d_in[10];
    const float* fc1w  = (const float*)d_in[11];
    const float* fc1b  = (const float*)d_in[12];
    const float* c2w   = (const float*)d_in[13];
    const float* c2b   = (const float*)d_in[14];

    char* ws = (char*)d_ws;
    short* Wf = (short*)(ws + OFF_WF);
    short* A0 = (short*)(ws + OFF_AB);
    short* A1 = (short*)(ws + OFF_AB + AB_ONE);
    float* x    = (float*)(ws + OFF_X);
    float* ua   = (float*)(ws + OFF_UA);
    float* bsum = (float*)(ws + OFF_BS);
    float* accW = (float*)(ws + OFF_AC);
    float* accO = (float*)(ws + OFF_AC + ACC_HALF);
    float* cst  = (float*)(ws + OFF_CS);

    prep_x<<<(B_N * L_N) / 256, 256, 0, stream>>>(input, mask, w1, b1, cw, cb, x, ua);
    prep_wf<<<16 * 17, 256, 0, stream>>>(w_ih, w_hh, Wf);
    prep_bs<<<(G_N + 255) / 256, 256, 0, stream>>>(b_ih, b_hh, bsum);
    prep_zero<<<(B_N * 1088 + 255) / 256, 256, 0, stream>>>((unsigned int*)A0, cst, accW);

    RParams P;
    P.mask = mask; P.bias_mat = biasm; P.fc1_w = fc1w; P.fc1_b = fc1b;
    P.conv2_w = c2w; P.conv2_b = c2b; P.Wf = Wf;
    P.x = x; P.ua = ua; P.bsum = bsum; P.accW = accW; P.accO = accO;
    P.cstate = cst; P.out = out;

    short* bufs[2] = { A0, A1 };
    for (int t = 0; t < T_N; ++t) {
        P.Ain  = bufs[t & 1];
        P.Aout = bufs[t & 1];
        ctx_step<<<B_N / 4, 256, 0, stream>>>(P, t);
        P.Ain  = bufs[t & 1];
        P.Aout = bufs[(t + 1) & 1];
        gemm_cell_step<<<512, 256, 0, stream>>>(P);
    }
    P.Ain = bufs[T_N & 1];
    P.Aout = bufs[T_N & 1];
    ctx_step<<<B_N / 4, 256, 0, stream>>>(P, T_N);
}